// Round 1
// baseline (1377.213 us; speedup 1.0000x reference)
//
#include <hip/hip_runtime.h>

#define T_LEN 8196
#define INF_F 1e10f

// ---------------------------------------------------------------- helpers
__device__ __forceinline__ float softmin3(float a, float b, float c) {
    float m = fminf(fminf(a, b), c);
    float s = __expf(m - a) + __expf(m - b) + __expf(m - c);
    return m - __logf(s);
}
__device__ __forceinline__ float sigm(float x) { return 1.0f / (1.0f + __expf(-x)); }
__device__ __forceinline__ float tanh_f(float x) {
    x = fminf(fmaxf(x, -15.0f), 15.0f);
    float e = __expf(2.0f * x);
    return (e - 1.0f) / (e + 1.0f);
}

// ------------------------------------------- prep: transpose weights, zero sync
// wt layout (floats): Wih1^T [72][384] @0, Whh1^T [128][384] @27648,
//                     Wih2^T [128][384] @76800, Whh2^T [128][384] @125952
__global__ void k_prep(const float* __restrict__ Wih1, const float* __restrict__ Whh1,
                       const float* __restrict__ Wih2, const float* __restrict__ Whh2,
                       float* __restrict__ wt, int* __restrict__ prog) {
    int gid = blockIdx.x * 256 + threadIdx.x;
    if (gid < 32) prog[gid] = 0;
    if (gid >= 175104) return;
    if (gid < 27648) {
        int k = gid / 384, g = gid % 384;
        wt[gid] = Wih1[g * 72 + k];
    } else if (gid < 76800) {
        int r = gid - 27648; int k = r / 384, g = r % 384;
        wt[gid] = Whh1[g * 128 + k];
    } else if (gid < 125952) {
        int r = gid - 76800; int k = r / 384, g = r % 384;
        wt[gid] = Wih2[g * 128 + k];
    } else {
        int r = gid - 125952; int k = r / 384, g = r % 384;
        wt[gid] = Whh2[g * 128 + k];
    }
}

// ------------------------------------------- GRU features
// 256 blocks: seq = bx>>7, window base = (bx&127)*16. 256 threads:
// u = tid&127 (hidden unit), wg = tid>>7 (two groups of 8 windows).
// seq[t][b][j*3+c] = x[j][c][b*4+t]
__global__ __launch_bounds__(256)
void k_gru(const float* __restrict__ X, const float* __restrict__ Y,
           const float* __restrict__ wt,
           const float* __restrict__ bih1, const float* __restrict__ bhh1,
           const float* __restrict__ bih2, const float* __restrict__ bhh2,
           const float* __restrict__ W1, const float* __restrict__ b1,
           float* __restrict__ fbuf) {
    __shared__ __align__(16) float xb[72 * 20];    // [k][16 windows], pad 20
    __shared__ __align__(16) float h1l[128 * 20];
    __shared__ __align__(16) float h2l[128 * 20];

    const int tid = threadIdx.x;
    const int u = tid & 127;
    const int w0 = (tid >> 7) * 8;
    const int bx = blockIdx.x;
    const int seq = bx >> 7;
    const int wbase = (bx & 127) << 4;
    const float* xp = seq ? Y : X;

    const float* wih1 = wt;
    const float* whh1 = wt + 27648;
    const float* wih2 = wt + 76800;
    const float* whh2 = wt + 125952;

    const float br1  = bih1[u] + bhh1[u];
    const float bz1  = bih1[128 + u] + bhh1[128 + u];
    const float bni1 = bih1[256 + u];
    const float bnh1 = bhh1[256 + u];
    const float br2  = bih2[u] + bhh2[u];
    const float bz2  = bih2[128 + u] + bhh2[128 + u];
    const float bni2 = bih2[256 + u];
    const float bnh2 = bhh2[256 + u];

    float h1r[8], h2r[8];
#pragma unroll
    for (int j = 0; j < 8; ++j) { h1r[j] = 0.f; h2r[j] = 0.f; }
    for (int e = tid; e < 128 * 20; e += 256) { h1l[e] = 0.f; h2l[e] = 0.f; }
    __syncthreads();

    for (int t = 0; t < 8; ++t) {
        // stage input slice for this timestep
        for (int e = tid; e < 72 * 16; e += 256) {
            int k = e >> 4, w = e & 15;
            int jj = k / 3, c = k - jj * 3;
            xb[k * 20 + w] = xp[jj * (3 * T_LEN) + c * T_LEN + ((wbase + w) << 2) + t];
        }
        __syncthreads();

        // ---- layer 1
        float ar[8], az[8], ai[8], ah[8];
#pragma unroll
        for (int j = 0; j < 8; ++j) { ar[j] = br1; az[j] = bz1; ai[j] = bni1; ah[j] = bnh1; }
        for (int k = 0; k < 72; ++k) {
            float wr = wih1[k * 384 + u];
            float wz = wih1[k * 384 + 128 + u];
            float wn = wih1[k * 384 + 256 + u];
            const float4 x0 = *(const float4*)&xb[k * 20 + w0];
            const float4 x1 = *(const float4*)&xb[k * 20 + w0 + 4];
            float xv[8] = {x0.x, x0.y, x0.z, x0.w, x1.x, x1.y, x1.z, x1.w};
#pragma unroll
            for (int j = 0; j < 8; ++j) {
                ar[j] = fmaf(wr, xv[j], ar[j]);
                az[j] = fmaf(wz, xv[j], az[j]);
                ai[j] = fmaf(wn, xv[j], ai[j]);
            }
        }
        for (int k = 0; k < 128; ++k) {
            float wr = whh1[k * 384 + u];
            float wz = whh1[k * 384 + 128 + u];
            float wn = whh1[k * 384 + 256 + u];
            const float4 x0 = *(const float4*)&h1l[k * 20 + w0];
            const float4 x1 = *(const float4*)&h1l[k * 20 + w0 + 4];
            float xv[8] = {x0.x, x0.y, x0.z, x0.w, x1.x, x1.y, x1.z, x1.w};
#pragma unroll
            for (int j = 0; j < 8; ++j) {
                ar[j] = fmaf(wr, xv[j], ar[j]);
                az[j] = fmaf(wz, xv[j], az[j]);
                ah[j] = fmaf(wn, xv[j], ah[j]);
            }
        }
        __syncthreads();   // all reads of old h1 done
#pragma unroll
        for (int j = 0; j < 8; ++j) {
            float r = sigm(ar[j]);
            float z = sigm(az[j]);
            float n = tanh_f(ai[j] + r * ah[j]);
            h1r[j] = (1.f - z) * n + z * h1r[j];
        }
#pragma unroll
        for (int j = 0; j < 8; ++j) h1l[u * 20 + w0 + j] = h1r[j];
        __syncthreads();   // new h1 visible

        // ---- layer 2
#pragma unroll
        for (int j = 0; j < 8; ++j) { ar[j] = br2; az[j] = bz2; ai[j] = bni2; ah[j] = bnh2; }
        for (int k = 0; k < 128; ++k) {
            float wr = wih2[k * 384 + u];
            float wz = wih2[k * 384 + 128 + u];
            float wn = wih2[k * 384 + 256 + u];
            const float4 x0 = *(const float4*)&h1l[k * 20 + w0];
            const float4 x1 = *(const float4*)&h1l[k * 20 + w0 + 4];
            float xv[8] = {x0.x, x0.y, x0.z, x0.w, x1.x, x1.y, x1.z, x1.w};
#pragma unroll
            for (int j = 0; j < 8; ++j) {
                ar[j] = fmaf(wr, xv[j], ar[j]);
                az[j] = fmaf(wz, xv[j], az[j]);
                ai[j] = fmaf(wn, xv[j], ai[j]);
            }
        }
        for (int k = 0; k < 128; ++k) {
            float wr = whh2[k * 384 + u];
            float wz = whh2[k * 384 + 128 + u];
            float wn = whh2[k * 384 + 256 + u];
            const float4 x0 = *(const float4*)&h2l[k * 20 + w0];
            const float4 x1 = *(const float4*)&h2l[k * 20 + w0 + 4];
            float xv[8] = {x0.x, x0.y, x0.z, x0.w, x1.x, x1.y, x1.z, x1.w};
#pragma unroll
            for (int j = 0; j < 8; ++j) {
                ar[j] = fmaf(wr, xv[j], ar[j]);
                az[j] = fmaf(wz, xv[j], az[j]);
                ah[j] = fmaf(wn, xv[j], ah[j]);
            }
        }
        __syncthreads();   // all reads of old h2 done
#pragma unroll
        for (int j = 0; j < 8; ++j) {
            float r = sigm(ar[j]);
            float z = sigm(az[j]);
            float n = tanh_f(ai[j] + r * ah[j]);
            h2r[j] = (1.f - z) * n + z * h2r[j];
        }
#pragma unroll
        for (int j = 0; j < 8; ++j) h2l[u * 20 + w0 + j] = h2r[j];
        __syncthreads();
    }

    // epilogue: f = h2 @ W1^T + b1, stored padded to 32
    for (int idx = tid; idx < 16 * 30; idx += 256) {
        int w = idx / 30, ff = idx - w * 30;
        float acc = b1[ff];
        for (int k = 0; k < 128; ++k) acc = fmaf(h2l[k * 20 + w], W1[ff * 128 + k], acc);
        fbuf[(seq * 2048 + wbase + w) * 32 + ff] = acc;
    }
}

// ------------------------------------------- pairwise sqdist, row-major D[i][j]
__global__ __launch_bounds__(256)
void k_pair(const float* __restrict__ fbuf, float* __restrict__ D) {
    __shared__ float f1t[64 * 33];
    __shared__ float f2t[64 * 33];
    const int tid = threadIdx.x;
    const int i0 = blockIdx.y * 64, j0 = blockIdx.x * 64;
    for (int e = tid; e < 64 * 32; e += 256) {
        int r = e >> 5, c = e & 31;
        f1t[r * 33 + c] = fbuf[(i0 + r) * 32 + c];
        f2t[r * 33 + c] = fbuf[(2048 + j0 + r) * 32 + c];
    }
    __syncthreads();
    const int tx = tid & 15, ty = tid >> 4;
    float acc[4][4];
#pragma unroll
    for (int r = 0; r < 4; ++r)
#pragma unroll
        for (int c = 0; c < 4; ++c) acc[r][c] = 0.f;
    for (int k = 0; k < 30; ++k) {
        float a[4], b[4];
#pragma unroll
        for (int r = 0; r < 4; ++r) a[r] = f1t[(ty * 4 + r) * 33 + k];
#pragma unroll
        for (int c = 0; c < 4; ++c) b[c] = f2t[(tx * 4 + c) * 33 + k];
#pragma unroll
        for (int r = 0; r < 4; ++r)
#pragma unroll
            for (int c = 0; c < 4; ++c) {
                float d = a[r] - b[c];
                acc[r][c] = fmaf(d, d, acc[r][c]);
            }
    }
#pragma unroll
    for (int r = 0; r < 4; ++r) {
        float4 v = make_float4(acc[r][0], acc[r][1], acc[r][2], acc[r][3]);
        *(float4*)&D[(i0 + ty * 4 + r) * 2048 + j0 + tx * 4] = v;
    }
}

// ------------------------------------------- softDTW wavefront
// 16 blocks x 64 lanes; lane i owns rows rA=128b+2i, rB=rA+1.
// At step t lane i computes column j = t - i for both its rows.
// Cross-lane dep via shfl_up; cross-block via bnd[] + acquire/release prog[].
#define DTW_BATCH(CUR_A, CUR_B, NXT_A, NXT_B, T0)                               \
  {                                                                             \
    const int t0 = (T0);                                                        \
    _Pragma("unroll")                                                           \
    for (int u2 = 0; u2 < 16; ++u2) {   /* prefetch next batch's D */           \
        int jj = t0 + 16 + u2 - lane;                                           \
        int jc = min(max(jj, 0), 2047);                                         \
        NXT_A[u2] = D[rA * 2048 + jc];                                          \
        NXT_B[u2] = D[rB * 2048 + jc];                                          \
    }                                                                           \
    if (b > 0) {                                                                \
        int need = min(t0 + 16, 2048);                                          \
        while (__hip_atomic_load(&prog[b - 1], __ATOMIC_ACQUIRE,                \
                                 __HIP_MEMORY_SCOPE_AGENT) < need)              \
            __builtin_amdgcn_s_sleep(4);                                        \
        _Pragma("unroll")                                                       \
        for (int u2 = 0; u2 < 16; ++u2) bnd16[u2] = bprev[min(t0 + u2, 2047)];  \
    }                                                                           \
    _Pragma("unroll")                                                           \
    for (int u2 = 0; u2 < 16; ++u2) {                                           \
        const int t = t0 + u2;                                                  \
        const int j = t - lane;                                                 \
        const bool valid = (j >= 0) && (j < 2048);                              \
        float upA, dgA;                                                         \
        if (b == 0) { upA = INF_F; dgA = (j == 0) ? 0.f : INF_F; }              \
        else { upA = bnd16[u2]; dgA = (u2 == 0) ? bnd_carry : bnd16[u2 - 1]; }  \
        if (lane > 0) { upA = s1; dgA = s1p; }                                  \
        float vA = valid ? (CUR_A[u2] + softmin3(dgA, upA, aL)) : INF_F;        \
        float vB = valid ? (CUR_B[u2] + softmin3(aL, vA, bL)) : INF_F;          \
        s1p = s1;                                                               \
        s1 = __shfl_up(vB, 1);                                                  \
        aL = vA; bL = vB;                                                       \
        if (lane == 63 && valid) {                                              \
            if (b < 15) bmine[j] = vB;                                          \
            else if (j == 2047) res = vB;                                       \
        }                                                                       \
    }                                                                           \
    if (b > 0) bnd_carry = bnd16[15];                                           \
    if (b < 15) {                                                               \
        __threadfence();                                                        \
        if (lane == 63)                                                         \
            __hip_atomic_store(&prog[b], t0 - 47, __ATOMIC_RELEASE,             \
                               __HIP_MEMORY_SCOPE_AGENT);                       \
    }                                                                           \
  }

__global__ __launch_bounds__(64)
void k_dtw(const float* __restrict__ D, float* __restrict__ bnd,
           int* prog, float* __restrict__ out) {
    const int b = blockIdx.x;
    const int lane = threadIdx.x;
    const int rA = b * 128 + 2 * lane;
    const int rB = rA + 1;
    const float* bprev = bnd + (b - 1) * 2048;
    float* bmine = bnd + b * 2048;

    float aL = INF_F, bL = INF_F;     // left values (col j-1) for rows rA,rB
    float s1 = INF_F, s1p = INF_F;    // shfl history of lane-1's row-rB values
    float bnd_carry = INF_F;
    float res = 0.f;
    float bnd16[16];

    float dA0[16], dB0[16], dA1[16], dB1[16];
#pragma unroll
    for (int u2 = 0; u2 < 16; ++u2) {   // preload batch 0
        int jj = u2 - lane;
        int jc = min(max(jj, 0), 2047);
        dA0[u2] = D[rA * 2048 + jc];
        dB0[u2] = D[rB * 2048 + jc];
    }

    // 132 batches of 16 steps cover t = 0 .. 2111 (need t up to 2110)
    for (int bt = 0; bt < 132; bt += 2) {
        DTW_BATCH(dA0, dB0, dA1, dB1, bt * 16);
        DTW_BATCH(dA1, dB1, dA0, dB0, (bt + 1) * 16);
    }

    if (b == 15 && lane == 63) out[0] = res;
}

// ------------------------------------------- launch
extern "C" void kernel_launch(void* const* d_in, const int* in_sizes, int n_in,
                              void* d_out, int out_size, void* d_ws, size_t ws_size,
                              hipStream_t stream) {
    const float* X    = (const float*)d_in[0];
    const float* Y    = (const float*)d_in[1];
    const float* Wih1 = (const float*)d_in[2];
    const float* Whh1 = (const float*)d_in[3];
    const float* bih1 = (const float*)d_in[4];
    const float* bhh1 = (const float*)d_in[5];
    const float* Wih2 = (const float*)d_in[6];
    const float* Whh2 = (const float*)d_in[7];
    const float* bih2 = (const float*)d_in[8];
    const float* bhh2 = (const float*)d_in[9];
    const float* W1   = (const float*)d_in[10];
    const float* b1   = (const float*)d_in[11];
    float* out = (float*)d_out;

    float* ws   = (float*)d_ws;
    float* wt   = ws;                      // 175104 floats
    float* fbuf = wt + 175104;             // 2*2048*32 = 131072
    float* Dm   = fbuf + 131072;           // 2048*2048
    float* bnd  = Dm + 2048 * 2048;        // 16*2048
    int*   prog = (int*)(bnd + 16 * 2048); // 32 ints   (~18.1 MB total)

    k_prep<<<684, 256, 0, stream>>>(Wih1, Whh1, Wih2, Whh2, wt, prog);
    k_gru<<<256, 256, 0, stream>>>(X, Y, wt, bih1, bhh1, bih2, bhh2, W1, b1, fbuf);
    k_pair<<<dim3(32, 32), 256, 0, stream>>>(fbuf, Dm);
    k_dtw<<<16, 64, 0, stream>>>(Dm, bnd, prog, out);
}

// Round 2
// 1275.742 us; speedup vs baseline: 1.0795x; 1.0795x over previous
//
#include <hip/hip_runtime.h>
#include <stdint.h>

#define T_LEN 8196
#define INF_F 1e10f

// ---------------------------------------------------------------- helpers
__device__ __forceinline__ float softmin3(float a, float b, float c) {
    float m = fminf(fminf(a, b), c);
    float s = __expf(m - a) + __expf(m - b) + __expf(m - c);
    return m - __logf(s);
}
__device__ __forceinline__ float sigm(float x) { return 1.0f / (1.0f + __expf(-x)); }
__device__ __forceinline__ float tanh_f(float x) {
    x = fminf(fmaxf(x, -15.0f), 15.0f);
    float e = __expf(2.0f * x);
    return (e - 1.0f) / (e + 1.0f);
}

// ------------------------------------------- prep: transpose weights
// wt layout (floats): Wih1^T [72][384] @0, Whh1^T [128][384] @27648,
//                     Wih2^T [128][384] @76800, Whh2^T [128][384] @125952
__global__ void k_prep(const float* __restrict__ Wih1, const float* __restrict__ Whh1,
                       const float* __restrict__ Wih2, const float* __restrict__ Whh2,
                       float* __restrict__ wt) {
    int gid = blockIdx.x * 256 + threadIdx.x;
    if (gid >= 175104) return;
    if (gid < 27648) {
        int k = gid / 384, g = gid % 384;
        wt[gid] = Wih1[g * 72 + k];
    } else if (gid < 76800) {
        int r = gid - 27648; int k = r / 384, g = r % 384;
        wt[gid] = Whh1[g * 128 + k];
    } else if (gid < 125952) {
        int r = gid - 76800; int k = r / 384, g = r % 384;
        wt[gid] = Wih2[g * 128 + k];
    } else {
        int r = gid - 125952; int k = r / 384, g = r % 384;
        wt[gid] = Whh2[g * 128 + k];
    }
}

// ------------------------------------------- GRU features
// 256 blocks: seq = bx>>7, window base = (bx&127)*16. 256 threads:
// u = tid&127 (hidden unit), wg = tid>>7 (two groups of 8 windows).
// seq[t][b][j*3+c] = x[j][c][b*4+t]
__global__ __launch_bounds__(256)
void k_gru(const float* __restrict__ X, const float* __restrict__ Y,
           const float* __restrict__ wt,
           const float* __restrict__ bih1, const float* __restrict__ bhh1,
           const float* __restrict__ bih2, const float* __restrict__ bhh2,
           const float* __restrict__ W1, const float* __restrict__ b1,
           float* __restrict__ fbuf) {
    __shared__ __align__(16) float xb[72 * 20];    // [k][16 windows], pad 20
    __shared__ __align__(16) float h1l[128 * 20];
    __shared__ __align__(16) float h2l[128 * 20];

    const int tid = threadIdx.x;
    const int u = tid & 127;
    const int w0 = (tid >> 7) * 8;
    const int bx = blockIdx.x;
    const int seq = bx >> 7;
    const int wbase = (bx & 127) << 4;
    const float* xp = seq ? Y : X;

    const float* wih1 = wt;
    const float* whh1 = wt + 27648;
    const float* wih2 = wt + 76800;
    const float* whh2 = wt + 125952;

    const float br1  = bih1[u] + bhh1[u];
    const float bz1  = bih1[128 + u] + bhh1[128 + u];
    const float bni1 = bih1[256 + u];
    const float bnh1 = bhh1[256 + u];
    const float br2  = bih2[u] + bhh2[u];
    const float bz2  = bih2[128 + u] + bhh2[128 + u];
    const float bni2 = bih2[256 + u];
    const float bnh2 = bhh2[256 + u];

    float h1r[8], h2r[8];
#pragma unroll
    for (int j = 0; j < 8; ++j) { h1r[j] = 0.f; h2r[j] = 0.f; }
    for (int e = tid; e < 128 * 20; e += 256) { h1l[e] = 0.f; h2l[e] = 0.f; }
    __syncthreads();

    for (int t = 0; t < 8; ++t) {
        // stage input slice for this timestep
        for (int e = tid; e < 72 * 16; e += 256) {
            int k = e >> 4, w = e & 15;
            int jj = k / 3, c = k - jj * 3;
            xb[k * 20 + w] = xp[jj * (3 * T_LEN) + c * T_LEN + ((wbase + w) << 2) + t];
        }
        __syncthreads();

        // ---- layer 1
        float ar[8], az[8], ai[8], ah[8];
#pragma unroll
        for (int j = 0; j < 8; ++j) { ar[j] = br1; az[j] = bz1; ai[j] = bni1; ah[j] = bnh1; }
        for (int k = 0; k < 72; ++k) {
            float wr = wih1[k * 384 + u];
            float wz = wih1[k * 384 + 128 + u];
            float wn = wih1[k * 384 + 256 + u];
            const float4 x0 = *(const float4*)&xb[k * 20 + w0];
            const float4 x1 = *(const float4*)&xb[k * 20 + w0 + 4];
            float xv[8] = {x0.x, x0.y, x0.z, x0.w, x1.x, x1.y, x1.z, x1.w};
#pragma unroll
            for (int j = 0; j < 8; ++j) {
                ar[j] = fmaf(wr, xv[j], ar[j]);
                az[j] = fmaf(wz, xv[j], az[j]);
                ai[j] = fmaf(wn, xv[j], ai[j]);
            }
        }
        for (int k = 0; k < 128; ++k) {
            float wr = whh1[k * 384 + u];
            float wz = whh1[k * 384 + 128 + u];
            float wn = whh1[k * 384 + 256 + u];
            const float4 x0 = *(const float4*)&h1l[k * 20 + w0];
            const float4 x1 = *(const float4*)&h1l[k * 20 + w0 + 4];
            float xv[8] = {x0.x, x0.y, x0.z, x0.w, x1.x, x1.y, x1.z, x1.w};
#pragma unroll
            for (int j = 0; j < 8; ++j) {
                ar[j] = fmaf(wr, xv[j], ar[j]);
                az[j] = fmaf(wz, xv[j], az[j]);
                ah[j] = fmaf(wn, xv[j], ah[j]);
            }
        }
        __syncthreads();   // all reads of old h1 done
#pragma unroll
        for (int j = 0; j < 8; ++j) {
            float r = sigm(ar[j]);
            float z = sigm(az[j]);
            float n = tanh_f(ai[j] + r * ah[j]);
            h1r[j] = (1.f - z) * n + z * h1r[j];
        }
#pragma unroll
        for (int j = 0; j < 8; ++j) h1l[u * 20 + w0 + j] = h1r[j];
        __syncthreads();   // new h1 visible

        // ---- layer 2
#pragma unroll
        for (int j = 0; j < 8; ++j) { ar[j] = br2; az[j] = bz2; ai[j] = bni2; ah[j] = bnh2; }
        for (int k = 0; k < 128; ++k) {
            float wr = wih2[k * 384 + u];
            float wz = wih2[k * 384 + 128 + u];
            float wn = wih2[k * 384 + 256 + u];
            const float4 x0 = *(const float4*)&h1l[k * 20 + w0];
            const float4 x1 = *(const float4*)&h1l[k * 20 + w0 + 4];
            float xv[8] = {x0.x, x0.y, x0.z, x0.w, x1.x, x1.y, x1.z, x1.w};
#pragma unroll
            for (int j = 0; j < 8; ++j) {
                ar[j] = fmaf(wr, xv[j], ar[j]);
                az[j] = fmaf(wz, xv[j], az[j]);
                ai[j] = fmaf(wn, xv[j], ai[j]);
            }
        }
        for (int k = 0; k < 128; ++k) {
            float wr = whh2[k * 384 + u];
            float wz = whh2[k * 384 + 128 + u];
            float wn = whh2[k * 384 + 256 + u];
            const float4 x0 = *(const float4*)&h2l[k * 20 + w0];
            const float4 x1 = *(const float4*)&h2l[k * 20 + w0 + 4];
            float xv[8] = {x0.x, x0.y, x0.z, x0.w, x1.x, x1.y, x1.z, x1.w};
#pragma unroll
            for (int j = 0; j < 8; ++j) {
                ar[j] = fmaf(wr, xv[j], ar[j]);
                az[j] = fmaf(wz, xv[j], az[j]);
                ah[j] = fmaf(wn, xv[j], ah[j]);
            }
        }
        __syncthreads();   // all reads of old h2 done
#pragma unroll
        for (int j = 0; j < 8; ++j) {
            float r = sigm(ar[j]);
            float z = sigm(az[j]);
            float n = tanh_f(ai[j] + r * ah[j]);
            h2r[j] = (1.f - z) * n + z * h2r[j];
        }
#pragma unroll
        for (int j = 0; j < 8; ++j) h2l[u * 20 + w0 + j] = h2r[j];
        __syncthreads();
    }

    // epilogue: f = h2 @ W1^T + b1, stored padded to 32
    for (int idx = tid; idx < 16 * 30; idx += 256) {
        int w = idx / 30, ff = idx - w * 30;
        float acc = b1[ff];
        for (int k = 0; k < 128; ++k) acc = fmaf(h2l[k * 20 + w], W1[ff * 128 + k], acc);
        fbuf[(seq * 2048 + wbase + w) * 32 + ff] = acc;
    }
}

// ------------------------------------------- pairwise sqdist, row-major D[i][j]
__global__ __launch_bounds__(256)
void k_pair(const float* __restrict__ fbuf, float* __restrict__ D) {
    __shared__ float f1t[64 * 33];
    __shared__ float f2t[64 * 33];
    const int tid = threadIdx.x;
    const int i0 = blockIdx.y * 64, j0 = blockIdx.x * 64;
    for (int e = tid; e < 64 * 32; e += 256) {
        int r = e >> 5, c = e & 31;
        f1t[r * 33 + c] = fbuf[(i0 + r) * 32 + c];
        f2t[r * 33 + c] = fbuf[(2048 + j0 + r) * 32 + c];
    }
    __syncthreads();
    const int tx = tid & 15, ty = tid >> 4;
    float acc[4][4];
#pragma unroll
    for (int r = 0; r < 4; ++r)
#pragma unroll
        for (int c = 0; c < 4; ++c) acc[r][c] = 0.f;
    for (int k = 0; k < 30; ++k) {
        float a[4], b[4];
#pragma unroll
        for (int r = 0; r < 4; ++r) a[r] = f1t[(ty * 4 + r) * 33 + k];
#pragma unroll
        for (int c = 0; c < 4; ++c) b[c] = f2t[(tx * 4 + c) * 33 + k];
#pragma unroll
        for (int r = 0; r < 4; ++r)
#pragma unroll
            for (int c = 0; c < 4; ++c) {
                float d = a[r] - b[c];
                acc[r][c] = fmaf(d, d, acc[r][c]);
            }
    }
#pragma unroll
    for (int r = 0; r < 4; ++r) {
        float4 v = make_float4(acc[r][0], acc[r][1], acc[r][2], acc[r][3]);
        *(float4*)&D[(i0 + ty * 4 + r) * 2048 + j0 + tx * 4] = v;
    }
}

// ------------------------------------------- softDTW wavefront
// 16 blocks x 64 lanes; lane i owns rows rA=128b+2i, rB=rA+1.
// At step t lane i computes column j = t - i for both its rows.
// Cross-lane dep via shfl_up; cross-block via PACKED (tag<<32|f32bits)
// relaxed device-scope 64-bit atomics -- NO fences (the round-1 threadfence
// forced an L2 writeback per batch, ~15K cycles, and was the bottleneck).
#define DTW_BATCH(CUR_A, CUR_B, NXT_A, NXT_B, T0)                               \
  {                                                                             \
    const int t0 = (T0);                                                        \
    _Pragma("unroll")                                                           \
    for (int u2 = 0; u2 < 16; ++u2) {   /* prefetch next batch's D */           \
        int jj = t0 + 16 + u2 - lane;                                           \
        int jc = min(max(jj, 0), 2047);                                         \
        NXT_A[u2] = D[rA * 2048 + jc];                                          \
        NXT_B[u2] = D[rB * 2048 + jc];                                          \
    }                                                                           \
    if (b > 0) {                                                                \
        uint64_t pv[16];                                                        \
        _Pragma("unroll")                                                       \
        for (int u2 = 0; u2 < 16; ++u2) {   /* issue all 16, overlap latency */ \
            int jc = min(t0 + u2, 2047);                                        \
            pv[u2] = __hip_atomic_load(&bprevp[jc], __ATOMIC_RELAXED,           \
                                       __HIP_MEMORY_SCOPE_AGENT);               \
        }                                                                       \
        _Pragma("unroll")                                                       \
        for (int u2 = 0; u2 < 16; ++u2) {   /* re-poll stragglers */            \
            int jc = min(t0 + u2, 2047);                                        \
            while ((uint32_t)(pv[u2] >> 32) != (uint32_t)jc) {                  \
                __builtin_amdgcn_s_sleep(1);                                    \
                pv[u2] = __hip_atomic_load(&bprevp[jc], __ATOMIC_RELAXED,       \
                                           __HIP_MEMORY_SCOPE_AGENT);           \
            }                                                                   \
            bnd16[u2] = __uint_as_float((uint32_t)pv[u2]);                      \
        }                                                                       \
    }                                                                           \
    _Pragma("unroll")                                                           \
    for (int u2 = 0; u2 < 16; ++u2) {                                           \
        const int t = t0 + u2;                                                  \
        const int j = t - lane;                                                 \
        const bool valid = (j >= 0) && (j < 2048);                              \
        float upA, dgA;                                                         \
        if (b == 0) { upA = INF_F; dgA = (j == 0) ? 0.f : INF_F; }              \
        else { upA = bnd16[u2]; dgA = (u2 == 0) ? bnd_carry : bnd16[u2 - 1]; }  \
        if (lane > 0) { upA = s1; dgA = s1p; }                                  \
        float vA = valid ? (CUR_A[u2] + softmin3(dgA, upA, aL)) : INF_F;        \
        float vB = valid ? (CUR_B[u2] + softmin3(aL, vA, bL)) : INF_F;          \
        s1p = s1;                                                               \
        s1 = __shfl_up(vB, 1);                                                  \
        aL = vA; bL = vB;                                                       \
        if (lane == 63 && valid) {                                              \
            if (b < 15) {                                                       \
                uint64_t pk = ((uint64_t)(uint32_t)j << 32) |                   \
                              (uint64_t)__float_as_uint(vB);                    \
                __hip_atomic_store(&bminep[j], pk, __ATOMIC_RELAXED,            \
                                   __HIP_MEMORY_SCOPE_AGENT);                   \
            } else if (j == 2047) res = vB;                                     \
        }                                                                       \
    }                                                                           \
    if (b > 0) bnd_carry = bnd16[15];                                           \
  }

__global__ __launch_bounds__(64)
void k_dtw(const float* __restrict__ D, uint64_t* bndp, float* __restrict__ out) {
    const int b = blockIdx.x;
    const int lane = threadIdx.x;
    const int rA = b * 128 + 2 * lane;
    const int rB = rA + 1;
    const uint64_t* bprevp = bndp + (b - 1) * 2048;
    uint64_t* bminep = bndp + b * 2048;

    float aL = INF_F, bL = INF_F;     // left values (col j-1) for rows rA,rB
    float s1 = INF_F, s1p = INF_F;    // shfl history of lane-1's row-rB values
    float bnd_carry = INF_F;
    float res = 0.f;
    float bnd16[16];

    float dA0[16], dB0[16], dA1[16], dB1[16];
#pragma unroll
    for (int u2 = 0; u2 < 16; ++u2) {   // preload batch 0
        int jj = u2 - lane;
        int jc = min(max(jj, 0), 2047);
        dA0[u2] = D[rA * 2048 + jc];
        dB0[u2] = D[rB * 2048 + jc];
    }

    // 132 batches of 16 steps cover t = 0 .. 2111 (need t up to 2110)
    for (int bt = 0; bt < 132; bt += 2) {
        DTW_BATCH(dA0, dB0, dA1, dB1, bt * 16);
        DTW_BATCH(dA1, dB1, dA0, dB0, (bt + 1) * 16);
    }

    if (b == 15 && lane == 63) out[0] = res;
}

// ------------------------------------------- launch
extern "C" void kernel_launch(void* const* d_in, const int* in_sizes, int n_in,
                              void* d_out, int out_size, void* d_ws, size_t ws_size,
                              hipStream_t stream) {
    const float* X    = (const float*)d_in[0];
    const float* Y    = (const float*)d_in[1];
    const float* Wih1 = (const float*)d_in[2];
    const float* Whh1 = (const float*)d_in[3];
    const float* bih1 = (const float*)d_in[4];
    const float* bhh1 = (const float*)d_in[5];
    const float* Wih2 = (const float*)d_in[6];
    const float* Whh2 = (const float*)d_in[7];
    const float* bih2 = (const float*)d_in[8];
    const float* bhh2 = (const float*)d_in[9];
    const float* W1   = (const float*)d_in[10];
    const float* b1   = (const float*)d_in[11];
    float* out = (float*)d_out;

    float* ws   = (float*)d_ws;
    float* wt   = ws;                      // 175104 floats
    float* fbuf = wt + 175104;             // 2*2048*32 = 131072
    float* Dm   = fbuf + 131072;           // 2048*2048
    uint64_t* bndp = (uint64_t*)(Dm + 2048 * 2048);  // 16*2048 packed (tag|val)

    k_prep<<<684, 256, 0, stream>>>(Wih1, Whh1, Wih2, Whh2, wt);
    k_gru<<<256, 256, 0, stream>>>(X, Y, wt, bih1, bhh1, bih2, bhh2, W1, b1, fbuf);
    k_pair<<<dim3(32, 32), 256, 0, stream>>>(fbuf, Dm);
    k_dtw<<<16, 64, 0, stream>>>(Dm, bndp, out);
}